// Round 2
// baseline (596.589 us; speedup 1.0000x reference)
//
#include <hip/hip_runtime.h>
#include <cstdint>
#include <cstddef>

typedef unsigned short u16;
typedef __attribute__((ext_vector_type(4))) float f32x4;
typedef __attribute__((ext_vector_type(8))) short s16x8;

#define D_EMB 1024
#define NSEQ 1024
#define NB 8
#define NH 16
#define HS 64
#define DFF 4096
#define MTOT (NB*NSEQ)

__device__ __forceinline__ u16 f2bf(float f){
  unsigned u = __float_as_uint(f);
  u += 0x7FFFu + ((u >> 16) & 1u);     // round-to-nearest-even
  return (u16)(u >> 16);
}

// ---------------- tiled transpose + fp32->bf16 convert ----------------
// out[z][c][r] = in[z][r][c]
__global__ void transpose_cvt(const float* __restrict__ in, u16* __restrict__ out,
                              int R, int C, size_t inStride, size_t outStride){
  __shared__ float t[32][33];
  const float* ip = in + (size_t)blockIdx.z * inStride;
  u16* op = out + (size_t)blockIdx.z * outStride;
  int c0 = blockIdx.x * 32, r0 = blockIdx.y * 32;
  int tx = threadIdx.x, ty = threadIdx.y;
#pragma unroll
  for (int j = 0; j < 32; j += 8)
    t[ty + j][tx] = ip[(size_t)(r0 + ty + j) * C + (c0 + tx)];
  __syncthreads();
#pragma unroll
  for (int j = 0; j < 32; j += 8)
    op[(size_t)(c0 + ty + j) * R + (r0 + tx)] = f2bf(t[tx][ty + j]);
}

// ---------------- LayerNorm (fp32 in, bf16 out) ----------------
__global__ __launch_bounds__(256) void ln_kernel(const float* __restrict__ x,
    const float* __restrict__ g, const float* __restrict__ bb, u16* __restrict__ out){
  int row = blockIdx.x;
  const float* xr = x + (size_t)row * D_EMB;
  int c = threadIdx.x * 4;
  f32x4 v = *(const f32x4*)(xr + c);
  float s1 = v[0] + v[1] + v[2] + v[3];
  float s2 = v[0]*v[0] + v[1]*v[1] + v[2]*v[2] + v[3]*v[3];
#pragma unroll
  for (int m = 32; m > 0; m >>= 1){ s1 += __shfl_xor(s1, m); s2 += __shfl_xor(s2, m); }
  __shared__ float ps1[4], ps2[4];
  int w = threadIdx.x >> 6;
  if ((threadIdx.x & 63) == 0){ ps1[w] = s1; ps2[w] = s2; }
  __syncthreads();
  s1 = ps1[0] + ps1[1] + ps1[2] + ps1[3];
  s2 = ps2[0] + ps2[1] + ps2[2] + ps2[3];
  float mu = s1 * (1.f / D_EMB);
  float var = s2 * (1.f / D_EMB) - mu * mu;
  float rs = rsqrtf(var + 1e-5f);
  ushort4 o;
  o.x = f2bf((v[0]-mu)*rs*g[c+0] + bb[c+0]);
  o.y = f2bf((v[1]-mu)*rs*g[c+1] + bb[c+1]);
  o.z = f2bf((v[2]-mu)*rs*g[c+2] + bb[c+2]);
  o.w = f2bf((v[3]-mu)*rs*g[c+3] + bb[c+3]);
  *(ushort4*)(out + (size_t)row * D_EMB + c) = o;
}

// ---------------- GEMM: C = A[M,K] * Bt[N,K]^T, bf16 in, fp32 acc ----------------
#define BM 128
#define BN 128
#define BK 32

__device__ __forceinline__ void gload_lds16(const void* g, void* l){
  __builtin_amdgcn_global_load_lds((const __attribute__((address_space(1))) void*)g,
                                   (__attribute__((address_space(3))) void*)l, 16, 0, 0);
}

// MODE 0: QKV   -> o0=Q(bf16 [M,1024]), o1=K(bf16 [M,1024]), o2=VT(bf16 [B,H,HS,N]); bias0/1/2
// MODE 1: resid -> o0=fp32 [M,N] = resid + acc + bias0
// MODE 2: ff1   -> o0=bf16 [M,N] = leakyrelu(acc + bias0)
template<int MODE>
__global__ __launch_bounds__(256) void gemm_bt(
    const u16* __restrict__ A, const u16* __restrict__ Bt,
    int M, int N, int K,
    const float* __restrict__ bias0, const float* __restrict__ bias1,
    const float* __restrict__ bias2, const float* __restrict__ resid,
    void* __restrict__ o0, void* __restrict__ o1, void* __restrict__ o2)
{
  __shared__ alignas(16) u16 Al[2][BM*BK];
  __shared__ alignas(16) u16 Bl[2][BN*BK];
  const int tid = threadIdx.x;
  const int m0 = blockIdx.x * BM, n0 = blockIdx.y * BN;
  const int wid = tid >> 6, lane = tid & 63;
  const int wm = (wid >> 1) * 64, wn = (wid & 1) * 64;
  const int lr = lane & 15, lg = lane >> 4;

  f32x4 zero = {0.f, 0.f, 0.f, 0.f};
  f32x4 acc[4][4];
#pragma unroll
  for (int i = 0; i < 4; i++)
#pragma unroll
    for (int j = 0; j < 4; j++) acc[i][j] = zero;

  const int nk = K / BK;
  const int arow = tid >> 2, akg = tid & 3;   // arow 0..63, akg*8 = k-slice

  // full tile = 128 rows x 32 k of bf16 = 4096 elems; 256 thr x 16B covers half,
  // so each thread stages rows arow and arow+64 (LDS dest stays base+lane*16B).
  auto stage = [&](int bufi, int kt){
    const int k0 = kt * BK;
    const u16* ap = A  + (size_t)(m0 + arow) * K + k0 + akg * 8;
    gload_lds16(ap,                  &Al[bufi][tid * 8]);
    gload_lds16(ap + (size_t)64 * K, &Al[bufi][2048 + tid * 8]);
    const u16* bp = Bt + (size_t)(n0 + arow) * K + k0 + akg * 8;
    gload_lds16(bp,                  &Bl[bufi][tid * 8]);
    gload_lds16(bp + (size_t)64 * K, &Bl[bufi][2048 + tid * 8]);
  };

  stage(0, 0);
  for (int kt = 0; kt < nk; ++kt){
    __syncthreads();                       // drains vmcnt: stage(kt) complete for all waves
    if (kt + 1 < nk) stage((kt + 1) & 1, kt + 1);   // prefetch in flight during compute
    const int bufi = kt & 1;
    s16x8 af[4], bfr[4];
#pragma unroll
    for (int i = 0; i < 4; i++){
      af[i]  = *(const s16x8*)&Al[bufi][(wm + i*16 + lr) * BK + lg * 8];
      bfr[i] = *(const s16x8*)&Bl[bufi][(wn + i*16 + lr) * BK + lg * 8];
    }
#pragma unroll
    for (int i = 0; i < 4; i++)
#pragma unroll
      for (int j = 0; j < 4; j++)
        acc[i][j] = __builtin_amdgcn_mfma_f32_16x16x32_bf16(af[i], bfr[j], acc[i][j], 0, 0, 0);
  }

  // epilogue: lane holds C[row=lg*4+i][col=lr] per 16x16 fragment
#pragma unroll
  for (int fm = 0; fm < 4; fm++){
    const int gmb = m0 + wm + fm * 16 + lg * 4;
#pragma unroll
    for (int fn = 0; fn < 4; fn++){
      const int gn = n0 + wn + fn * 16 + lr;
#pragma unroll
      for (int i = 0; i < 4; i++){
        const int gm = gmb + i;
        float v = acc[fm][fn][i];
        if (MODE == 0){
          const int cls = gn >> 10, nn = gn & 1023;
          if (cls == 0)      ((u16*)o0)[(size_t)gm * D_EMB + nn] = f2bf(v + bias0[nn]);
          else if (cls == 1) ((u16*)o1)[(size_t)gm * D_EMB + nn] = f2bf(v + bias1[nn]);
          else {
            const int hh = nn >> 6, ss = nn & 63, bb = gm >> 10, tt = gm & 1023;
            ((u16*)o2)[(((size_t)(bb * NH + hh)) * HS + ss) * NSEQ + tt] = f2bf(v + bias2[nn]);
          }
        } else if (MODE == 1){
          ((float*)o0)[(size_t)gm * N + gn] = resid[(size_t)gm * N + gn] + v + bias0[gn];
        } else {
          float y = v + bias0[gn];
          y = y > 0.f ? y : 0.01f * y;
          ((u16*)o0)[(size_t)gm * N + gn] = f2bf(y);
        }
      }
    }
  }
}

// ---------------- flash attention: 1 block per (b,h,64-row Q tile) ----------------
__global__ __launch_bounds__(256) void attn_kernel(
    const u16* __restrict__ Qb, const u16* __restrict__ Kb, const u16* __restrict__ VT,
    u16* __restrict__ attnC)
{
  const int blk = blockIdx.x;
  const int qt = blk & 15, bh = blk >> 4;
  const int b = bh >> 4, h = bh & 15;
  const int tid = threadIdx.x, w = tid >> 6, lane = tid & 63;
  const int lr = lane & 15, lg = lane >> 4;
  const int t0 = qt * 64 + w * 16;

  __shared__ alignas(16) u16 Pl[4][16][72];   // per-wave P tile, padded (row stride 144B = 9*16B)

  const u16* qp = Qb + ((size_t)(b * NSEQ + t0 + lr)) * D_EMB + h * HS;
  s16x8 aq0 = *(const s16x8*)(qp + lg * 8);
  s16x8 aq1 = *(const s16x8*)(qp + 32 + lg * 8);

  float m_i[4], l_i[4];
  f32x4 zero = {0.f, 0.f, 0.f, 0.f};
  f32x4 ao[4];
#pragma unroll
  for (int i = 0; i < 4; i++){ m_i[i] = -1e30f; l_i[i] = 0.f; ao[i] = zero; }

  const float scale = 0.125f;   // 1/sqrt(64)

  for (int kt = 0; kt < NSEQ / 64; ++kt){
    const int tk = kt * 64;
    f32x4 sv[4];
#pragma unroll
    for (int fn = 0; fn < 4; fn++) sv[fn] = zero;
#pragma unroll
    for (int fn = 0; fn < 4; fn++){
      const u16* kp = Kb + ((size_t)(b * NSEQ + tk + fn * 16 + lr)) * D_EMB + h * HS;
      s16x8 bk0 = *(const s16x8*)(kp + lg * 8);
      s16x8 bk1 = *(const s16x8*)(kp + 32 + lg * 8);
      sv[fn] = __builtin_amdgcn_mfma_f32_16x16x32_bf16(aq0, bk0, sv[fn], 0, 0, 0);
      sv[fn] = __builtin_amdgcn_mfma_f32_16x16x32_bf16(aq1, bk1, sv[fn], 0, 0, 0);
    }
#pragma unroll
    for (int fn = 0; fn < 4; fn++) sv[fn] *= scale;

    float p[4][4];
#pragma unroll
    for (int i = 0; i < 4; i++){
      float rmax = fmaxf(fmaxf(sv[0][i], sv[1][i]), fmaxf(sv[2][i], sv[3][i]));
#pragma unroll
      for (int mm = 8; mm > 0; mm >>= 1) rmax = fmaxf(rmax, __shfl_xor(rmax, mm));
      float mnew = fmaxf(m_i[i], rmax);
      float fac = __expf(m_i[i] - mnew);
      float rs = 0.f;
#pragma unroll
      for (int fn = 0; fn < 4; fn++){ float pv = __expf(sv[fn][i] - mnew); p[fn][i] = pv; rs += pv; }
#pragma unroll
      for (int mm = 8; mm > 0; mm >>= 1) rs += __shfl_xor(rs, mm);
      l_i[i] = l_i[i] * fac + rs;
      m_i[i] = mnew;
#pragma unroll
      for (int fn = 0; fn < 4; fn++) ao[fn][i] = ao[fn][i] * fac;
    }

    // P (C-layout) -> per-wave LDS -> A-layout fragments (within-wave LDS RAW is ordered)
#pragma unroll
    for (int fn = 0; fn < 4; fn++)
#pragma unroll
      for (int i = 0; i < 4; i++)
        Pl[w][lg * 4 + i][fn * 16 + lr] = f2bf(p[fn][i]);

    s16x8 pa0 = *(const s16x8*)&Pl[w][lr][lg * 8];
    s16x8 pa1 = *(const s16x8*)&Pl[w][lr][32 + lg * 8];

#pragma unroll
    for (int fn = 0; fn < 4; fn++){
      const u16* vp = VT + (((size_t)(b * NH + h)) * HS + fn * 16 + lr) * NSEQ + tk;
      s16x8 v0 = *(const s16x8*)(vp + lg * 8);
      s16x8 v1 = *(const s16x8*)(vp + 32 + lg * 8);
      ao[fn] = __builtin_amdgcn_mfma_f32_16x16x32_bf16(pa0, v0, ao[fn], 0, 0, 0);
      ao[fn] = __builtin_amdgcn_mfma_f32_16x16x32_bf16(pa1, v1, ao[fn], 0, 0, 0);
    }
  }

#pragma unroll
  for (int fn = 0; fn < 4; fn++)
#pragma unroll
    for (int i = 0; i < 4; i++){
      float v = ao[fn][i] / l_i[i];
      attnC[((size_t)(b * NSEQ + t0 + lg * 4 + i)) * D_EMB + h * HS + fn * 16 + lr] = f2bf(v);
    }
}

// ---------------- host ----------------
extern "C" void kernel_launch(void* const* d_in, const int* in_sizes, int n_in,
                              void* d_out, int out_size, void* d_ws, size_t ws_size,
                              hipStream_t stream)
{
  const float* x    = (const float*)d_in[0];
  const float* Wq   = (const float*)d_in[1];
  const float* bq   = (const float*)d_in[2];
  const float* Wk   = (const float*)d_in[3];
  const float* bk   = (const float*)d_in[4];
  const float* Wv   = (const float*)d_in[5];
  const float* bv   = (const float*)d_in[6];
  const float* Wp   = (const float*)d_in[7];
  const float* bp   = (const float*)d_in[8];
  const float* W1   = (const float*)d_in[9];
  const float* b1   = (const float*)d_in[10];
  const float* W2   = (const float*)d_in[11];
  const float* b2   = (const float*)d_in[12];
  const float* ln1g = (const float*)d_in[13];
  const float* ln1b = (const float*)d_in[14];
  const float* ln2g = (const float*)d_in[15];
  const float* ln2b = (const float*)d_in[16];
  float* out = (float*)d_out;

  char* ws = (char*)d_ws;
  size_t off = 0;
  auto mk = [&](size_t bytes)->void*{ void* p = ws + off; off += (bytes + 255) & ~(size_t)255; return p; };
  u16*  h1    = (u16*) mk((size_t)MTOT * D_EMB * 2);
  u16*  Qb    = (u16*) mk((size_t)MTOT * D_EMB * 2);
  u16*  Kb    = (u16*) mk((size_t)MTOT * D_EMB * 2);
  u16*  VTb   = (u16*) mk((size_t)MTOT * D_EMB * 2);
  u16*  attnC = (u16*) mk((size_t)MTOT * D_EMB * 2);
  float* x1   = (float*)mk((size_t)MTOT * D_EMB * 4);
  u16*  h2    = (u16*) mk((size_t)MTOT * D_EMB * 2);
  u16*  ffb   = (u16*) mk((size_t)MTOT * DFF * 2);
  u16*  WqkvT = (u16*) mk((size_t)3 * D_EMB * D_EMB * 2);
  u16*  WpT   = (u16*) mk((size_t)D_EMB * D_EMB * 2);
  u16*  W1T   = (u16*) mk((size_t)D_EMB * DFF * 2);
  u16*  W2T   = (u16*) mk((size_t)D_EMB * DFF * 2);

  dim3 tb(32, 8, 1);
  // per-head [D][HS] -> [HS][D], heads batched on z; Wqkv stacked as rows [0,1024),[1024,2048),[2048,3072)
  transpose_cvt<<<dim3(HS/32, D_EMB/32, NH), tb, 0, stream>>>(Wq, WqkvT,                             D_EMB, HS, (size_t)D_EMB*HS, (size_t)HS*D_EMB);
  transpose_cvt<<<dim3(HS/32, D_EMB/32, NH), tb, 0, stream>>>(Wk, WqkvT + (size_t)D_EMB*D_EMB,       D_EMB, HS, (size_t)D_EMB*HS, (size_t)HS*D_EMB);
  transpose_cvt<<<dim3(HS/32, D_EMB/32, NH), tb, 0, stream>>>(Wv, WqkvT + (size_t)2*D_EMB*D_EMB,     D_EMB, HS, (size_t)D_EMB*HS, (size_t)HS*D_EMB);
  transpose_cvt<<<dim3(D_EMB/32, D_EMB/32, 1), tb, 0, stream>>>(Wp, WpT,  D_EMB, D_EMB, 0, 0);
  transpose_cvt<<<dim3(DFF/32,  D_EMB/32, 1), tb, 0, stream>>>(W1, W1T,  D_EMB, DFF,   0, 0);
  transpose_cvt<<<dim3(D_EMB/32, DFF/32,  1), tb, 0, stream>>>(W2, W2T,  DFF,   D_EMB, 0, 0);

  ln_kernel<<<MTOT, 256, 0, stream>>>(x, ln1g, ln1b, h1);

  gemm_bt<0><<<dim3(MTOT/BM, (3*D_EMB)/BN), 256, 0, stream>>>(h1, WqkvT, MTOT, 3*D_EMB, D_EMB,
      bq, bk, bv, nullptr, Qb, Kb, VTb);

  attn_kernel<<<NB*NH*(NSEQ/64), 256, 0, stream>>>(Qb, Kb, VTb, attnC);

  gemm_bt<1><<<dim3(MTOT/BM, D_EMB/BN), 256, 0, stream>>>(attnC, WpT, MTOT, D_EMB, D_EMB,
      bp, nullptr, nullptr, x, x1, nullptr, nullptr);

  ln_kernel<<<MTOT, 256, 0, stream>>>(x1, ln2g, ln2b, h2);

  gemm_bt<2><<<dim3(MTOT/BM, DFF/BN), 256, 0, stream>>>(h2, W1T, MTOT, DFF, D_EMB,
      b1, nullptr, nullptr, nullptr, ffb, nullptr, nullptr);

  gemm_bt<1><<<dim3(MTOT/BM, D_EMB/BN), 256, 0, stream>>>(ffb, W2T, MTOT, D_EMB, DFF,
      b2, nullptr, nullptr, x1, out, nullptr, nullptr);
}

// Round 3
// 470.883 us; speedup vs baseline: 1.2670x; 1.2670x over previous
//
#include <hip/hip_runtime.h>
#include <cstdint>
#include <cstddef>

typedef unsigned short u16;
typedef __attribute__((ext_vector_type(4))) float f32x4;
typedef __attribute__((ext_vector_type(8))) short s16x8;

#define D_EMB 1024
#define NSEQ 1024
#define NB 8
#define NH 16
#define HS 64
#define DFF 4096
#define MTOT (NB*NSEQ)

__device__ __forceinline__ u16 f2bf(float f){
  unsigned u = __float_as_uint(f);
  u += 0x7FFFu + ((u >> 16) & 1u);     // round-to-nearest-even
  return (u16)(u >> 16);
}

// ---------------- tiled transpose + fp32->bf16 convert ----------------
// out[z][c][r] = in[z][r][c]
__global__ void transpose_cvt(const float* __restrict__ in, u16* __restrict__ out,
                              int R, int C, size_t inStride, size_t outStride){
  __shared__ float t[32][33];
  const float* ip = in + (size_t)blockIdx.z * inStride;
  u16* op = out + (size_t)blockIdx.z * outStride;
  int c0 = blockIdx.x * 32, r0 = blockIdx.y * 32;
  int tx = threadIdx.x, ty = threadIdx.y;
#pragma unroll
  for (int j = 0; j < 32; j += 8)
    t[ty + j][tx] = ip[(size_t)(r0 + ty + j) * C + (c0 + tx)];
  __syncthreads();
#pragma unroll
  for (int j = 0; j < 32; j += 8)
    op[(size_t)(c0 + ty + j) * R + (r0 + tx)] = f2bf(t[tx][ty + j]);
}

// ---------------- LayerNorm (fp32 in, bf16 out) ----------------
__global__ __launch_bounds__(256) void ln_kernel(const float* __restrict__ x,
    const float* __restrict__ g, const float* __restrict__ bb, u16* __restrict__ out){
  int row = blockIdx.x;
  const float* xr = x + (size_t)row * D_EMB;
  int c = threadIdx.x * 4;
  f32x4 v = *(const f32x4*)(xr + c);
  float s1 = v[0] + v[1] + v[2] + v[3];
  float s2 = v[0]*v[0] + v[1]*v[1] + v[2]*v[2] + v[3]*v[3];
#pragma unroll
  for (int m = 32; m > 0; m >>= 1){ s1 += __shfl_xor(s1, m); s2 += __shfl_xor(s2, m); }
  __shared__ float ps1[4], ps2[4];
  int w = threadIdx.x >> 6;
  if ((threadIdx.x & 63) == 0){ ps1[w] = s1; ps2[w] = s2; }
  __syncthreads();
  s1 = ps1[0] + ps1[1] + ps1[2] + ps1[3];
  s2 = ps2[0] + ps2[1] + ps2[2] + ps2[3];
  float mu = s1 * (1.f / D_EMB);
  float var = s2 * (1.f / D_EMB) - mu * mu;
  float rs = rsqrtf(var + 1e-5f);
  ushort4 o;
  o.x = f2bf((v[0]-mu)*rs*g[c+0] + bb[c+0]);
  o.y = f2bf((v[1]-mu)*rs*g[c+1] + bb[c+1]);
  o.z = f2bf((v[2]-mu)*rs*g[c+2] + bb[c+2]);
  o.w = f2bf((v[3]-mu)*rs*g[c+3] + bb[c+3]);
  *(ushort4*)(out + (size_t)row * D_EMB + c) = o;
}

// ---------------- GEMM: C = A[M,K] * Bt[N,K]^T, bf16 in, fp32 acc ----------------
#define BM 128
#define BN 128
#define BK 32

__device__ __forceinline__ void gload_lds16(const void* g, void* l){
  __builtin_amdgcn_global_load_lds((const __attribute__((address_space(1))) void*)g,
                                   (__attribute__((address_space(3))) void*)l, 16, 0, 0);
}

// MODE 0: QKV   -> o0=Q(bf16 [M,1024]), o1=K(bf16 [M,1024]), o2=VT(bf16 [B,H,HS,N]); bias0/1/2
// MODE 1: resid -> o0=fp32 [M,N] = resid + acc + bias0
// MODE 2: ff1   -> o0=bf16 [M,N] = leakyrelu(acc + bias0)
template<int MODE>
__global__ __launch_bounds__(256) void gemm_bt(
    const u16* __restrict__ A, const u16* __restrict__ Bt,
    int M, int N, int K,
    const float* __restrict__ bias0, const float* __restrict__ bias1,
    const float* __restrict__ bias2, const float* __restrict__ resid,
    void* __restrict__ o0, void* __restrict__ o1, void* __restrict__ o2)
{
  __shared__ alignas(16) u16 Al[2][BM*BK];
  __shared__ alignas(16) u16 Bl[2][BN*BK];
  const int tid = threadIdx.x;
  const int m0 = blockIdx.x * BM, n0 = blockIdx.y * BN;
  const int wid = tid >> 6, lane = tid & 63;
  const int wm = (wid >> 1) * 64, wn = (wid & 1) * 64;
  const int lr = lane & 15, lg = lane >> 4;

  f32x4 zero = {0.f, 0.f, 0.f, 0.f};
  f32x4 acc[4][4];
#pragma unroll
  for (int i = 0; i < 4; i++)
#pragma unroll
    for (int j = 0; j < 4; j++) acc[i][j] = zero;

  const int nk = K / BK;
  const int arow = tid >> 2, akg = tid & 3;   // arow 0..63, akg*8 = k-slice

  auto stage = [&](int bufi, int kt){
    const int k0 = kt * BK;
    const u16* ap = A  + (size_t)(m0 + arow) * K + k0 + akg * 8;
    gload_lds16(ap,                  &Al[bufi][tid * 8]);
    gload_lds16(ap + (size_t)64 * K, &Al[bufi][2048 + tid * 8]);
    const u16* bp = Bt + (size_t)(n0 + arow) * K + k0 + akg * 8;
    gload_lds16(bp,                  &Bl[bufi][tid * 8]);
    gload_lds16(bp + (size_t)64 * K, &Bl[bufi][2048 + tid * 8]);
  };

  stage(0, 0);
  for (int kt = 0; kt < nk; ++kt){
    __syncthreads();                       // drains vmcnt: stage(kt) complete for all waves
    if (kt + 1 < nk) stage((kt + 1) & 1, kt + 1);   // prefetch in flight during compute
    const int bufi = kt & 1;
    s16x8 af[4], bfr[4];
#pragma unroll
    for (int i = 0; i < 4; i++){
      af[i]  = *(const s16x8*)&Al[bufi][(wm + i*16 + lr) * BK + lg * 8];
      bfr[i] = *(const s16x8*)&Bl[bufi][(wn + i*16 + lr) * BK + lg * 8];
    }
#pragma unroll
    for (int i = 0; i < 4; i++)
#pragma unroll
      for (int j = 0; j < 4; j++)
        acc[i][j] = __builtin_amdgcn_mfma_f32_16x16x32_bf16(af[i], bfr[j], acc[i][j], 0, 0, 0);
  }

  // epilogue: lane holds C[row=lg*4+i][col=lr] per 16x16 fragment
#pragma unroll
  for (int fm = 0; fm < 4; fm++){
    const int gmb = m0 + wm + fm * 16 + lg * 4;
#pragma unroll
    for (int fn = 0; fn < 4; fn++){
      const int gn = n0 + wn + fn * 16 + lr;
#pragma unroll
      for (int i = 0; i < 4; i++){
        const int gm = gmb + i;
        float v = acc[fm][fn][i];
        if (MODE == 0){
          const int cls = gn >> 10, nn = gn & 1023;
          if (cls == 0)      ((u16*)o0)[(size_t)gm * D_EMB + nn] = f2bf(v + bias0[nn]);
          else if (cls == 1) ((u16*)o1)[(size_t)gm * D_EMB + nn] = f2bf(v + bias1[nn]);
          else {
            const int hh = nn >> 6, ss = nn & 63, bb = gm >> 10, tt = gm & 1023;
            ((u16*)o2)[(((size_t)(bb * NH + hh)) * HS + ss) * NSEQ + tt] = f2bf(v + bias2[nn]);
          }
        } else if (MODE == 1){
          ((float*)o0)[(size_t)gm * N + gn] = resid[(size_t)gm * N + gn] + v + bias0[gn];
        } else {
          float y = v + bias0[gn];
          y = y > 0.f ? y : 0.01f * y;
          ((u16*)o0)[(size_t)gm * N + gn] = f2bf(y);
        }
      }
    }
  }
}

// ---------------- flash attention v2 ----------------
// 1 block = 256 thr = 4 waves; block owns 128 Q rows (wave: 32 rows = 2 frags).
// K/V tiles (64 seq x 64 hs) LDS-staged, double-buffered, XOR-swizzled.
// grid 1024: bh = bid&127 -> all 8 q-tiles of a (b,h) on one XCD (bid%8 rr).
__global__ __launch_bounds__(256) void attn_kernel(
    const u16* __restrict__ Qb, const u16* __restrict__ Kb, const u16* __restrict__ VT,
    u16* __restrict__ attnC)
{
  const int bid = blockIdx.x;
  const int bh = bid & 127, qt = bid >> 7;
  const int b = bh >> 4, h = bh & 15;
  const int tid = threadIdx.x, w = tid >> 6, lane = tid & 63;
  const int lr = lane & 15, lg = lane >> 4;
  const int q0 = qt * 128 + w * 32;

  __shared__ alignas(16) u16 Kl[2][64*64];   // [seq row][hs col] swizzled
  __shared__ alignas(16) u16 Vl[2][64*64];   // [hs row][seq col] swizzled
  __shared__ alignas(16) u16 Pl[4][32][72];  // per-wave P tile, padded

  const int srow = tid >> 3, scg = tid & 7;  // staging: row 0..31 (+32), chunk 0..7
  const u16* kbase = Kb + (size_t)(b * NSEQ) * D_EMB + h * HS;
  const u16* vbase = VT + ((size_t)(b * NH + h)) * HS * NSEQ;

  auto stage = [&](int buf, int kt){
    const int tk = kt * 64;
#pragma unroll
    for (int p = 0; p < 2; ++p){
      const int row = srow + p * 32;
      const int sc = scg ^ (row & 7);        // inverse-swizzled source chunk
      gload_lds16(kbase + (size_t)(tk + row) * D_EMB + sc * 8, &Kl[buf][(p * 256 + tid) * 8]);
      gload_lds16(vbase + (size_t)row * NSEQ + tk + sc * 8,    &Vl[buf][(p * 256 + tid) * 8]);
    }
  };

  // Q fragments: 32 rows x 64 cols, kept in registers for the whole pass
  s16x8 aq[2][2];
#pragma unroll
  for (int rb = 0; rb < 2; rb++)
#pragma unroll
    for (int kh = 0; kh < 2; kh++)
      aq[rb][kh] = *(const s16x8*)(Qb + (size_t)(b * NSEQ + q0 + rb * 16 + lr) * D_EMB
                                   + h * HS + kh * 32 + lg * 8);

  float m_i[2][4], l_i[2][4];
  f32x4 zero = {0.f, 0.f, 0.f, 0.f};
  f32x4 ao[2][4];
#pragma unroll
  for (int rb = 0; rb < 2; rb++)
#pragma unroll
    for (int i = 0; i < 4; i++){ m_i[rb][i] = -1e30f; l_i[rb][i] = 0.f; ao[rb][i] = zero; }

  const float scale = 0.125f;   // 1/sqrt(64)
  const int rsw = lr & 7;       // read-side swizzle key (row = fn*16+lr)

  stage(0, 0);
  for (int kt = 0; kt < NSEQ / 64; ++kt){
    __syncthreads();                          // stage(kt) complete for all waves
    if (kt + 1 < NSEQ / 64) stage((kt + 1) & 1, kt + 1);
    const int cur = kt & 1;

    // ---- QK^T ----
    f32x4 sv[2][4];
#pragma unroll
    for (int rb = 0; rb < 2; rb++)
#pragma unroll
      for (int fn = 0; fn < 4; fn++) sv[rb][fn] = zero;
#pragma unroll
    for (int fn = 0; fn < 4; fn++){
      const int krow = fn * 16 + lr;
#pragma unroll
      for (int kh = 0; kh < 2; kh++){
        const int chunk = (kh * 4 + lg) ^ rsw;
        s16x8 kf = *(const s16x8*)&Kl[cur][krow * 64 + chunk * 8];
        sv[0][fn] = __builtin_amdgcn_mfma_f32_16x16x32_bf16(aq[0][kh], kf, sv[0][fn], 0, 0, 0);
        sv[1][fn] = __builtin_amdgcn_mfma_f32_16x16x32_bf16(aq[1][kh], kf, sv[1][fn], 0, 0, 0);
      }
    }

    // ---- online softmax (per 16-row fragment; cols live across lr lanes) ----
#pragma unroll
    for (int rb = 0; rb < 2; rb++){
      float p[4][4];
#pragma unroll
      for (int i = 0; i < 4; i++){
        float s0 = sv[rb][0][i] * scale, s1 = sv[rb][1][i] * scale;
        float s2 = sv[rb][2][i] * scale, s3 = sv[rb][3][i] * scale;
        float rmax = fmaxf(fmaxf(s0, s1), fmaxf(s2, s3));
#pragma unroll
        for (int mm = 8; mm > 0; mm >>= 1) rmax = fmaxf(rmax, __shfl_xor(rmax, mm));
        float mnew = fmaxf(m_i[rb][i], rmax);
        float fac = __expf(m_i[rb][i] - mnew);
        float p0 = __expf(s0 - mnew), p1 = __expf(s1 - mnew);
        float p2 = __expf(s2 - mnew), p3 = __expf(s3 - mnew);
        p[0][i] = p0; p[1][i] = p1; p[2][i] = p2; p[3][i] = p3;
        float rs = (p0 + p1) + (p2 + p3);
#pragma unroll
        for (int mm = 8; mm > 0; mm >>= 1) rs += __shfl_xor(rs, mm);
        l_i[rb][i] = l_i[rb][i] * fac + rs;
        m_i[rb][i] = mnew;
#pragma unroll
        for (int fn = 0; fn < 4; fn++) ao[rb][fn][i] *= fac;
      }
      // P fragment (C-layout) -> per-wave LDS (A-layout source)
#pragma unroll
      for (int fn = 0; fn < 4; fn++)
#pragma unroll
        for (int i = 0; i < 4; i++)
          Pl[w][rb * 16 + lg * 4 + i][fn * 16 + lr] = f2bf(p[fn][i]);
    }

    // ---- PV ----
    s16x8 vf[4][2];
#pragma unroll
    for (int fn = 0; fn < 4; fn++){
      const int vrow = fn * 16 + lr;
#pragma unroll
      for (int kh = 0; kh < 2; kh++){
        const int chunk = (kh * 4 + lg) ^ rsw;
        vf[fn][kh] = *(const s16x8*)&Vl[cur][vrow * 64 + chunk * 8];
      }
    }
#pragma unroll
    for (int rb = 0; rb < 2; rb++){
      s16x8 pa0 = *(const s16x8*)&Pl[w][rb * 16 + lr][lg * 8];
      s16x8 pa1 = *(const s16x8*)&Pl[w][rb * 16 + lr][32 + lg * 8];
#pragma unroll
      for (int fn = 0; fn < 4; fn++){
        ao[rb][fn] = __builtin_amdgcn_mfma_f32_16x16x32_bf16(pa0, vf[fn][0], ao[rb][fn], 0, 0, 0);
        ao[rb][fn] = __builtin_amdgcn_mfma_f32_16x16x32_bf16(pa1, vf[fn][1], ao[rb][fn], 0, 0, 0);
      }
    }
  }

#pragma unroll
  for (int rb = 0; rb < 2; rb++)
#pragma unroll
    for (int fn = 0; fn < 4; fn++)
#pragma unroll
      for (int i = 0; i < 4; i++){
        float v = ao[rb][fn][i] / l_i[rb][i];
        attnC[(size_t)(b * NSEQ + q0 + rb * 16 + lg * 4 + i) * D_EMB + h * HS + fn * 16 + lr] = f2bf(v);
      }
}

// ---------------- host ----------------
extern "C" void kernel_launch(void* const* d_in, const int* in_sizes, int n_in,
                              void* d_out, int out_size, void* d_ws, size_t ws_size,
                              hipStream_t stream)
{
  const float* x    = (const float*)d_in[0];
  const float* Wq   = (const float*)d_in[1];
  const float* bq   = (const float*)d_in[2];
  const float* Wk   = (const float*)d_in[3];
  const float* bk   = (const float*)d_in[4];
  const float* Wv   = (const float*)d_in[5];
  const float* bv   = (const float*)d_in[6];
  const float* Wp   = (const float*)d_in[7];
  const float* bp   = (const float*)d_in[8];
  const float* W1   = (const float*)d_in[9];
  const float* b1   = (const float*)d_in[10];
  const float* W2   = (const float*)d_in[11];
  const float* b2   = (const float*)d_in[12];
  const float* ln1g = (const float*)d_in[13];
  const float* ln1b = (const float*)d_in[14];
  const float* ln2g = (const float*)d_in[15];
  const float* ln2b = (const float*)d_in[16];
  float* out = (float*)d_out;

  char* ws = (char*)d_ws;
  size_t off = 0;
  auto mk = [&](size_t bytes)->void*{ void* p = ws + off; off += (bytes + 255) & ~(size_t)255; return p; };
  u16*  h1    = (u16*) mk((size_t)MTOT * D_EMB * 2);
  u16*  Qb    = (u16*) mk((size_t)MTOT * D_EMB * 2);
  u16*  Kb    = (u16*) mk((size_t)MTOT * D_EMB * 2);
  u16*  VTb   = (u16*) mk((size_t)MTOT * D_EMB * 2);
  u16*  attnC = (u16*) mk((size_t)MTOT * D_EMB * 2);
  float* x1   = (float*)mk((size_t)MTOT * D_EMB * 4);
  u16*  h2    = (u16*) mk((size_t)MTOT * D_EMB * 2);
  u16*  ffb   = (u16*) mk((size_t)MTOT * DFF * 2);
  u16*  WqkvT = (u16*) mk((size_t)3 * D_EMB * D_EMB * 2);
  u16*  WpT   = (u16*) mk((size_t)D_EMB * D_EMB * 2);
  u16*  W1T   = (u16*) mk((size_t)D_EMB * DFF * 2);
  u16*  W2T   = (u16*) mk((size_t)D_EMB * DFF * 2);

  dim3 tb(32, 8, 1);
  transpose_cvt<<<dim3(HS/32, D_EMB/32, NH), tb, 0, stream>>>(Wq, WqkvT,                         D_EMB, HS, (size_t)D_EMB*HS, (size_t)HS*D_EMB);
  transpose_cvt<<<dim3(HS/32, D_EMB/32, NH), tb, 0, stream>>>(Wk, WqkvT + (size_t)D_EMB*D_EMB,   D_EMB, HS, (size_t)D_EMB*HS, (size_t)HS*D_EMB);
  transpose_cvt<<<dim3(HS/32, D_EMB/32, NH), tb, 0, stream>>>(Wv, WqkvT + (size_t)2*D_EMB*D_EMB, D_EMB, HS, (size_t)D_EMB*HS, (size_t)HS*D_EMB);
  transpose_cvt<<<dim3(D_EMB/32, D_EMB/32, 1), tb, 0, stream>>>(Wp, WpT,  D_EMB, D_EMB, 0, 0);
  transpose_cvt<<<dim3(DFF/32,  D_EMB/32, 1), tb, 0, stream>>>(W1, W1T,  D_EMB, DFF,   0, 0);
  transpose_cvt<<<dim3(D_EMB/32, DFF/32,  1), tb, 0, stream>>>(W2, W2T,  DFF,   D_EMB, 0, 0);

  ln_kernel<<<MTOT, 256, 0, stream>>>(x, ln1g, ln1b, h1);

  gemm_bt<0><<<dim3(MTOT/BM, (3*D_EMB)/BN), 256, 0, stream>>>(h1, WqkvT, MTOT, 3*D_EMB, D_EMB,
      bq, bk, bv, nullptr, Qb, Kb, VTb);

  attn_kernel<<<NB*NH*(NSEQ/128), 256, 0, stream>>>(Qb, Kb, VTb, attnC);

  gemm_bt<1><<<dim3(MTOT/BM, D_EMB/BN), 256, 0, stream>>>(attnC, WpT, MTOT, D_EMB, D_EMB,
      bp, nullptr, nullptr, x, x1, nullptr, nullptr);

  ln_kernel<<<MTOT, 256, 0, stream>>>(x1, ln2g, ln2b, h2);

  gemm_bt<2><<<dim3(MTOT/BM, DFF/BN), 256, 0, stream>>>(h2, W1T, MTOT, DFF, D_EMB,
      b1, nullptr, nullptr, nullptr, ffb, nullptr, nullptr);

  gemm_bt<1><<<dim3(MTOT/BM, D_EMB/BN), 256, 0, stream>>>(ffb, W2T, MTOT, D_EMB, DFF,
      b2, nullptr, nullptr, x1, out, nullptr, nullptr);
}